// Round 3
// baseline (1588.804 us; speedup 1.0000x reference)
//
#include <hip/hip_runtime.h>
#include <hip/hip_bf16.h>

// Problem constants (B=4, H=16, S=2048, D=64, fp32).
#define S_LEN 2048
#define DK    64
#define NT    32                   // number of 64-wide k-tiles
#define O_ELEMS (4 * 16 * 2048 * 64)       // 8388608 = B*H*S*D
#define MASK_ELEMS (4ull * 16 * 2048 * 2048) // 268435456

typedef float f32x4  __attribute__((ext_vector_type(4)));
typedef short bf16x8 __attribute__((ext_vector_type(8)));

static __device__ __forceinline__ unsigned short f2bf(float f) {
  // round-to-nearest-even fp32 -> bf16
  unsigned int u = __builtin_bit_cast(unsigned int, f);
  u += 0x7fffu + ((u >> 16) & 1u);
  return (unsigned short)(u >> 16);
}
static __device__ __forceinline__ float bf2f(unsigned short h) {
  unsigned int u = ((unsigned int)h) << 16;
  return __builtin_bit_cast(float, u);
}
static __device__ __forceinline__ bf16x8 ldb8(const unsigned short* p) {
  uint4 u = *(const uint4*)p;
  return __builtin_bit_cast(bf16x8, u);
}

// ---------------------------------------------------------------------------
// K -> (K_hi, K_lo) bf16 split, same [B,H,S,D] layout. grid 8192 x 256.
__global__ __launch_bounds__(256) void cvt_k_kernel(
    const float* __restrict__ k,
    unsigned short* __restrict__ k_hi,
    unsigned short* __restrict__ k_lo) {
  int i = blockIdx.x * 256 + threadIdx.x;   // one float4 per thread
  float4 v = ((const float4*)k)[i];
  ushort4 h, l;
  h.x = f2bf(v.x); l.x = f2bf(v.x - bf2f(h.x));
  h.y = f2bf(v.y); l.y = f2bf(v.y - bf2f(h.y));
  h.z = f2bf(v.z); l.z = f2bf(v.z - bf2f(h.z));
  h.w = f2bf(v.w); l.w = f2bf(v.w - bf2f(h.w));
  ((ushort4*)k_hi)[i] = h;
  ((ushort4*)k_lo)[i] = l;
}

// ---------------------------------------------------------------------------
// V [bh][j][d] fp32 -> V_t [bh][d][j] bf16. grid 2048 (= 64 bh * 32 j-tiles).
__global__ __launch_bounds__(256) void transpose_v_kernel(
    const float* __restrict__ v,
    unsigned short* __restrict__ v_t) {
  __shared__ float tile[64][65];   // +1 pad vs bank conflicts
  const int b  = blockIdx.x;
  const int bh = b >> 5;
  const int j0 = (b & 31) << 6;
  const int t  = threadIdx.x;
  #pragma unroll
  for (int i = 0; i < 4; ++i) {
    int flat = i * 256 + t;        // 0..1023
    int jl   = flat >> 4;          // row 0..63
    int f4   = flat & 15;          // float4 slot in row
    float4 x = *(const float4*)(v + ((size_t)bh * S_LEN + j0 + jl) * DK + f4 * 4);
    tile[jl][f4 * 4 + 0] = x.x;
    tile[jl][f4 * 4 + 1] = x.y;
    tile[jl][f4 * 4 + 2] = x.z;
    tile[jl][f4 * 4 + 3] = x.w;
  }
  __syncthreads();
  #pragma unroll
  for (int i = 0; i < 4; ++i) {
    int flat = i * 256 + t;
    int d    = flat >> 4;          // 0..63
    int jg   = (flat & 15) << 2;   // 0..60 step 4
    ushort4 o;
    o.x = f2bf(tile[jg + 0][d]);
    o.y = f2bf(tile[jg + 1][d]);
    o.z = f2bf(tile[jg + 2][d]);
    o.w = f2bf(tile[jg + 3][d]);
    *(ushort4*)(v_t + ((size_t)bh * DK + d) * S_LEN + j0 + jg) = o;
  }
}

// ---------------------------------------------------------------------------
// mask int32 [B,H,S,S] -> bit-packed (32:1), linear bit order.
// Each thread packs 32 consecutive ints (128 B) -> one uint32.
// Per-instruction lane stride is 128 B; all bytes of every L2 line are
// consumed across the 8 unrolled loads, so DRAM bursts are fully used.
__global__ __launch_bounds__(256) void pack_mask_kernel(
    const int* __restrict__ mask,
    unsigned int* __restrict__ bits) {
  const size_t tidg = (size_t)blockIdx.x * 256 + threadIdx.x;
  const int4* mp = (const int4*)(mask + tidg * 32);
  unsigned int b = 0;
  #pragma unroll
  for (int i = 0; i < 8; ++i) {
    int4 m = mp[i];
    b |= (unsigned)(m.x != 0) << (i * 4 + 0);
    b |= (unsigned)(m.y != 0) << (i * 4 + 1);
    b |= (unsigned)(m.z != 0) << (i * 4 + 2);
    b |= (unsigned)(m.w != 0) << (i * 4 + 3);
  }
  bits[tidg] = b;
}

// ---------------------------------------------------------------------------
// Fused attention: 1 block = 64 q-rows of one (b,h); 4 waves x 16 rows.
// Pass A: QK^T (split-bf16 3-MFMA) + packed mask bits -> row sums of exp.
// Pass B: recompute QK^T, normalize, write weights fp32, P->LDS->A-frag,
//         PV MFMA accumulate, write O.
// No __syncthreads anywhere: LDS is wave-private (wave_barrier only).
__global__ __launch_bounds__(256) void attn_main(
    const float* __restrict__ q,
    const unsigned long long* __restrict__ bits64,  // packed mask
    const unsigned short* __restrict__ k_hi,
    const unsigned short* __restrict__ k_lo,
    const unsigned short* __restrict__ v_t,
    float* __restrict__ out_o,
    float* __restrict__ out_w) {
  // XCD-aware remap: XCD = blk%8 gets a contiguous bh range (K/V stay in its L2)
  const int blk = blockIdx.x;                 // 0..2047
  const int id  = ((blk & 7) << 8) | (blk >> 3);
  const int bh  = id >> 5;                    // 0..63
  const int q0  = (id & 31) << 6;             // q-tile * 64

  const int tid = threadIdx.x;
  const int w   = tid >> 6;                   // wave 0..3
  const int ln  = tid & 63;
  const int l15 = ln & 15;
  const int lq  = ln >> 4;                    // quarter 0..3

  __shared__ __align__(16) unsigned short p_lds[4][16][72];  // per-wave, padded

  // ---- Q A-fragments (scaled by 1/8 then split hi/lo) ----
  bf16x8 qh[2], ql[2];
  {
    const float* qp = q + ((size_t)bh * S_LEN + q0 + (w << 4) + l15) * DK + (lq << 3);
    #pragma unroll
    for (int c = 0; c < 2; ++c) {
      float4 a = *(const float4*)(qp + c * 32);
      float4 b = *(const float4*)(qp + c * 32 + 4);
      float vv[8] = {a.x, a.y, a.z, a.w, b.x, b.y, b.z, b.w};
      #pragma unroll
      for (int i = 0; i < 8; ++i) {
        float s = vv[i] * 0.125f;             // exact (power of 2)
        unsigned short h = f2bf(s);
        qh[c][i] = (short)h;
        ql[c][i] = (short)f2bf(s - bf2f(h));
      }
    }
  }

  const size_t kbase  = ((size_t)bh * S_LEN + l15) * DK + (lq << 3);
  const size_t vtbase = ((size_t)bh * DK + l15) * S_LEN + (lq << 3);
  const size_t rowb   = (size_t)bh * S_LEN + q0 + (w << 4) + (lq << 2);
  const size_t mofs   = rowb * S_LEN + l15;   // weights offset
  const size_t oofs   = rowb * DK + l15;
  // packed-mask row base: 32 ulongs per row of 2048 bits
  const unsigned long long* brow = bits64 + rowb * 32;
  const int bsh = l15;                        // bit shift base (s*16 + l15)

  auto qk_tile = [&](int t, f32x4 (&acc)[4]) {
    #pragma unroll
    for (int s = 0; s < 4; ++s) {
      #pragma unroll
      for (int c = 0; c < 2; ++c) {
        const size_t ko = kbase + (size_t)t * 4096 + s * 1024 + c * 32;
        const bf16x8 bhf = ldb8(k_hi + ko);
        const bf16x8 blf = ldb8(k_lo + ko);
        acc[s] = __builtin_amdgcn_mfma_f32_16x16x32_bf16(ql[c], bhf, acc[s], 0, 0, 0);
        acc[s] = __builtin_amdgcn_mfma_f32_16x16x32_bf16(qh[c], blf, acc[s], 0, 0, 0);
        acc[s] = __builtin_amdgcn_mfma_f32_16x16x32_bf16(qh[c], bhf, acc[s], 0, 0, 0);
      }
    }
  };

  // ---------------- pass A: row sums of exp ----------------
  float sums[4] = {0.f, 0.f, 0.f, 0.f};
  for (int t = 0; t < NT; ++t) {
    unsigned long long mb[4];
    #pragma unroll
    for (int r = 0; r < 4; ++r) mb[r] = brow[r * 32 + t];   // issued early
    f32x4 acc[4];
    #pragma unroll
    for (int s = 0; s < 4; ++s) acc[s] = f32x4{0.f, 0.f, 0.f, 0.f};
    qk_tile(t, acc);
    #pragma unroll
    for (int s = 0; s < 4; ++s) {
      #pragma unroll
      for (int r = 0; r < 4; ++r) {
        const int m = (int)((mb[r] >> (s * 16 + bsh)) & 1ull);
        sums[r] += m ? 0.f : __expf(acc[s][r]);
      }
    }
  }
  // reduce across the 16 lanes sharing each row; then invert
  #pragma unroll
  for (int r = 0; r < 4; ++r) {
    float x = sums[r];
    x += __shfl_xor(x, 1, 64);
    x += __shfl_xor(x, 2, 64);
    x += __shfl_xor(x, 4, 64);
    x += __shfl_xor(x, 8, 64);
    sums[r] = 1.0f / x;                       // now holds 1/rowsum
  }

  // ---------------- pass B: weights + PV ----------------
  f32x4 oacc[4];
  #pragma unroll
  for (int s = 0; s < 4; ++s) oacc[s] = f32x4{0.f, 0.f, 0.f, 0.f};

  for (int t = 0; t < NT; ++t) {
    unsigned long long mb[4];
    #pragma unroll
    for (int r = 0; r < 4; ++r) mb[r] = brow[r * 32 + t];   // L2-hot
    f32x4 acc[4];
    #pragma unroll
    for (int s = 0; s < 4; ++s) acc[s] = f32x4{0.f, 0.f, 0.f, 0.f};
    qk_tile(t, acc);
    #pragma unroll
    for (int s = 0; s < 4; ++s) {
      #pragma unroll
      for (int r = 0; r < 4; ++r) {
        const int m  = (int)((mb[r] >> (s * 16 + bsh)) & 1ull);
        const float e  = m ? 0.f : __expf(acc[s][r]);
        const float wn = e * sums[r];
        out_w[mofs + (size_t)r * S_LEN + t * 64 + s * 16] = wn;
        p_lds[w][(lq << 2) + r][s * 16 + l15] = f2bf(wn);
      }
    }
    __builtin_amdgcn_wave_barrier();          // order P writes before reads
    #pragma unroll
    for (int c = 0; c < 2; ++c) {
      const bf16x8 pa = *(const bf16x8*)&p_lds[w][l15][c * 32 + (lq << 3)];
      #pragma unroll
      for (int s = 0; s < 4; ++s) {
        const bf16x8 vb = ldb8(v_t + vtbase + (size_t)s * (16 * S_LEN) + t * 64 + c * 32);
        oacc[s] = __builtin_amdgcn_mfma_f32_16x16x32_bf16(pa, vb, oacc[s], 0, 0, 0);
      }
    }
    __builtin_amdgcn_wave_barrier();          // P reads done before next tile's writes
  }

  #pragma unroll
  for (int s = 0; s < 4; ++s) {
    #pragma unroll
    for (int r = 0; r < 4; ++r) {
      out_o[oofs + (size_t)r * DK + s * 16] = oacc[s][r];
    }
  }
}

// ---------------------------------------------------------------------------
extern "C" void kernel_launch(void* const* d_in, const int* in_sizes, int n_in,
                              void* d_out, int out_size, void* d_ws, size_t ws_size,
                              hipStream_t stream) {
  (void)in_sizes; (void)n_in; (void)out_size; (void)ws_size;
  const float* q = (const float*)d_in[0];
  const float* k = (const float*)d_in[1];
  const float* v = (const float*)d_in[2];
  const int* mask = (const int*)d_in[3];      // bool_ -> int32

  float* out_o = (float*)d_out;               // [B,H,S,D] fp32
  float* out_w = out_o + (size_t)O_ELEMS;     // [B,H,S,S] fp32

  // workspace: K_hi, K_lo, V_t (3 x 16.8 MB) + packed mask bits (33.6 MB)
  //          = 83.9 MB required
  unsigned short* k_hi = (unsigned short*)d_ws;
  unsigned short* k_lo = k_hi + (size_t)O_ELEMS;
  unsigned short* v_t  = k_lo + (size_t)O_ELEMS;
  unsigned int*   bits = (unsigned int*)(v_t + (size_t)O_ELEMS);

  cvt_k_kernel<<<O_ELEMS / (256 * 4), 256, 0, stream>>>(k, k_hi, k_lo);
  transpose_v_kernel<<<2048, 256, 0, stream>>>(v, v_t);
  pack_mask_kernel<<<(int)(MASK_ELEMS / (256 * 32)), 256, 0, stream>>>(mask, bits);
  attn_main<<<2048, 256, 0, stream>>>(q, (const unsigned long long*)bits,
                                      k_hi, k_lo, v_t, out_o, out_w);
}

// Round 4
// 962.826 us; speedup vs baseline: 1.6501x; 1.6501x over previous
//
#include <hip/hip_runtime.h>
#include <hip/hip_bf16.h>

// Problem constants (B=4, H=16, S=2048, D=64, fp32).
#define S_LEN 2048
#define DK    64
#define NT    32                   // number of 64-wide k-tiles
#define O_ELEMS (4 * 16 * 2048 * 64)       // 8388608 = B*H*S*D
#define MASK_ELEMS (4ull * 16 * 2048 * 2048) // 268435456

typedef float f32x4  __attribute__((ext_vector_type(4)));
typedef short bf16x8 __attribute__((ext_vector_type(8)));

static __device__ __forceinline__ unsigned short f2bf(float f) {
  unsigned int u = __builtin_bit_cast(unsigned int, f);
  u += 0x7fffu + ((u >> 16) & 1u);
  return (unsigned short)(u >> 16);
}
static __device__ __forceinline__ float bf2f(unsigned short h) {
  unsigned int u = ((unsigned int)h) << 16;
  return __builtin_bit_cast(float, u);
}

// async global->LDS, 16B per lane; LDS dest = uniform base + lane*16
static __device__ __forceinline__ void gload_lds16(const void* g, void* l) {
  __builtin_amdgcn_global_load_lds(
      (const __attribute__((address_space(1))) unsigned int*)g,
      (__attribute__((address_space(3))) unsigned int*)l, 16, 0, 0);
}

// ---------------------------------------------------------------------------
// K -> (K_hi, K_lo) bf16 split, pre-scaled by log2(e)/8 (folds softmax scale
// and exp->exp2 conversion). Same [B,H,S,D] layout. grid 8192 x 256.
__global__ __launch_bounds__(256) void cvt_k_kernel(
    const float* __restrict__ k,
    unsigned short* __restrict__ k_hi,
    unsigned short* __restrict__ k_lo) {
  int i = blockIdx.x * 256 + threadIdx.x;
  float4 v = ((const float4*)k)[i];
  ushort4 h, l;
  h.x = f2bf(v.x); l.x = f2bf(v.x - bf2f(h.x));
  h.y = f2bf(v.y); l.y = f2bf(v.y - bf2f(h.y));
  h.z = f2bf(v.z); l.z = f2bf(v.z - bf2f(h.z));
  h.w = f2bf(v.w); l.w = f2bf(v.w - bf2f(h.w));
  ((ushort4*)k_hi)[i] = h;
  ((ushort4*)k_lo)[i] = l;
}

// ---------------------------------------------------------------------------
// V [bh][j][d] fp32 -> V_t [bh][d][j] bf16. grid 2048.
__global__ __launch_bounds__(256) void transpose_v_kernel(
    const float* __restrict__ v,
    unsigned short* __restrict__ v_t) {
  __shared__ float tile[64][65];
  const int b  = blockIdx.x;
  const int bh = b >> 5;
  const int j0 = (b & 31) << 6;
  const int t  = threadIdx.x;
  #pragma unroll
  for (int i = 0; i < 4; ++i) {
    int flat = i * 256 + t;
    int jl   = flat >> 4;
    int f4   = flat & 15;
    float4 x = *(const float4*)(v + ((size_t)bh * S_LEN + j0 + jl) * DK + f4 * 4);
    tile[jl][f4 * 4 + 0] = x.x;
    tile[jl][f4 * 4 + 1] = x.y;
    tile[jl][f4 * 4 + 2] = x.z;
    tile[jl][f4 * 4 + 3] = x.w;
  }
  __syncthreads();
  #pragma unroll
  for (int i = 0; i < 4; ++i) {
    int flat = i * 256 + t;
    int d    = flat >> 4;
    int jg   = (flat & 15) << 2;
    ushort4 o;
    o.x = f2bf(tile[jg + 0][d]);
    o.y = f2bf(tile[jg + 1][d]);
    o.z = f2bf(tile[jg + 2][d]);
    o.w = f2bf(tile[jg + 3][d]);
    *(ushort4*)(v_t + ((size_t)bh * DK + d) * S_LEN + j0 + jg) = o;
  }
}

// ---------------------------------------------------------------------------
// mask int32 -> bit-packed 32:1, linear bit order.
__global__ __launch_bounds__(256) void pack_mask_kernel(
    const int* __restrict__ mask,
    unsigned int* __restrict__ bits) {
  const size_t tidg = (size_t)blockIdx.x * 256 + threadIdx.x;
  const int4* mp = (const int4*)(mask + tidg * 32);
  unsigned int b = 0;
  #pragma unroll
  for (int i = 0; i < 8; ++i) {
    int4 m = mp[i];
    b |= (unsigned)(m.x != 0) << (i * 4 + 0);
    b |= (unsigned)(m.y != 0) << (i * 4 + 1);
    b |= (unsigned)(m.z != 0) << (i * 4 + 2);
    b |= (unsigned)(m.w != 0) << (i * 4 + 3);
  }
  bits[tidg] = b;
}

// ---------------------------------------------------------------------------
// Fused attention, LDS-staged double-buffered K/V.
// Block = 64 q-rows of one (b,h); 4 waves x 16 rows.
// Q pre-scaled by log2(e)/8 so scores are in log2 domain: exp = v_exp_f32.
// LDS tiles XOR-swizzled: stored[row][sc] = true chunk sc^(row&7); writer
// pre-swizzles the GLOBAL source per lane (global_load_lds dest is linear).
__global__ __launch_bounds__(256, 2) void attn_main(
    const float* __restrict__ q,
    const unsigned long long* __restrict__ bits64,
    const unsigned short* __restrict__ k_hi,
    const unsigned short* __restrict__ k_lo,
    const unsigned short* __restrict__ v_t,
    float* __restrict__ out_o,
    float* __restrict__ out_w) {
  const int blk = blockIdx.x;                 // 0..2047
  const int id  = ((blk & 7) << 8) | (blk >> 3);  // XCD-contig bh ranges
  const int bh  = id >> 5;                    // 0..63
  const int q0  = (id & 31) << 6;             // q-tile * 64

  const int tid = threadIdx.x;
  const int w   = tid >> 6;                   // wave 0..3
  const int ln  = tid & 63;
  const int l15 = ln & 15;
  const int lq  = ln >> 4;                    // 0..3

  __shared__ __align__(16) unsigned short kh_s[2][64][64];   // 16 KB
  __shared__ __align__(16) unsigned short kl_s[2][64][64];   // 16 KB
  __shared__ __align__(16) unsigned short vt_s[2][64][64];   // 16 KB
  __shared__ __align__(16) unsigned short p_lds[4][16][72];  // 9 KB

  // ---- staging source addressing (swizzled at the source, rule #21) ----
  const int srow   = ln >> 3;                 // row within 8-row group
  const int schunk = (ln & 7) ^ srow;         // pre-swizzled source chunk
  const size_t k_src0 = ((size_t)bh * S_LEN + (w << 4) + srow) * DK + schunk * 8;
  const size_t v_src0 = ((size_t)bh * DK + (w << 4) + srow) * S_LEN + schunk * 8;

  auto stage_K = [&](int t, int b) {
    #pragma unroll
    for (int u = 0; u < 2; ++u) {
      gload_lds16(k_hi + k_src0 + (size_t)t * 4096 + u * 512,
                  &kh_s[b][(w << 4) + u * 8][0]);
      gload_lds16(k_lo + k_src0 + (size_t)t * 4096 + u * 512,
                  &kl_s[b][(w << 4) + u * 8][0]);
    }
  };
  auto stage_V = [&](int t, int b) {
    #pragma unroll
    for (int u = 0; u < 2; ++u) {
      gload_lds16(v_t + v_src0 + (size_t)u * 16384 + t * 64,
                  &vt_s[b][(w << 4) + u * 8][0]);
    }
  };

  stage_K(0, 0);   // prologue DMA overlaps Q fragment prep below

  // ---- Q A-fragments: scale by log2(e)/8, split hi/lo ----
  bf16x8 qh[2], ql[2];
  {
    const float sc = 0.125f * 1.4426950408889634f;
    const float* qp = q + ((size_t)bh * S_LEN + q0 + (w << 4) + l15) * DK + (lq << 3);
    #pragma unroll
    for (int c = 0; c < 2; ++c) {
      float4 a = *(const float4*)(qp + c * 32);
      float4 b = *(const float4*)(qp + c * 32 + 4);
      float vv[8] = {a.x, a.y, a.z, a.w, b.x, b.y, b.z, b.w};
      #pragma unroll
      for (int i = 0; i < 8; ++i) {
        float s = vv[i] * sc;
        unsigned short h = f2bf(s);
        qh[c][i] = (short)h;
        ql[c][i] = (short)f2bf(s - bf2f(h));
      }
    }
  }

  const size_t rowb = (size_t)bh * S_LEN + q0 + (w << 4) + (lq << 2);
  const size_t mofs = rowb * S_LEN + l15;     // weights offset
  const size_t oofs = rowb * DK + l15;
  const unsigned long long* brow = bits64 + rowb * 32;
  const int bsh = l15;

  // fragment read from swizzled LDS tile: row = s*16+l15, chunk C^(row&7)
  auto qk_tile = [&](int b, f32x4 (&acc)[4]) {
    #pragma unroll
    for (int s = 0; s < 4; ++s) {
      #pragma unroll
      for (int c = 0; c < 2; ++c) {
        const int off = (s * 16 + l15) * 64 + (((((c << 2) | lq)) ^ (l15 & 7)) << 3);
        const bf16x8 bhf = *(const bf16x8*)(&kh_s[b][0][0] + off);
        const bf16x8 blf = *(const bf16x8*)(&kl_s[b][0][0] + off);
        acc[s] = __builtin_amdgcn_mfma_f32_16x16x32_bf16(ql[c], bhf, acc[s], 0, 0, 0);
        acc[s] = __builtin_amdgcn_mfma_f32_16x16x32_bf16(qh[c], blf, acc[s], 0, 0, 0);
        acc[s] = __builtin_amdgcn_mfma_f32_16x16x32_bf16(qh[c], bhf, acc[s], 0, 0, 0);
      }
    }
  };

  __syncthreads();                            // K tile 0 staged

  // ---------------- pass A: row sums of exp2 ----------------
  float sums[4] = {0.f, 0.f, 0.f, 0.f};
  for (int t = 0; t < NT; ++t) {
    const int b = t & 1;
    if (t + 1 < NT) stage_K(t + 1, b ^ 1);
    unsigned long long mb[4];
    #pragma unroll
    for (int r = 0; r < 4; ++r) mb[r] = brow[r * 32 + t];
    f32x4 acc[4];
    #pragma unroll
    for (int s = 0; s < 4; ++s) acc[s] = f32x4{0.f, 0.f, 0.f, 0.f};
    qk_tile(b, acc);
    #pragma unroll
    for (int s = 0; s < 4; ++s) {
      #pragma unroll
      for (int r = 0; r < 4; ++r) {
        const int m = (int)((mb[r] >> (s * 16 + bsh)) & 1ull);
        sums[r] += m ? 0.f : __builtin_amdgcn_exp2f(acc[s][r]);
      }
    }
    __syncthreads();                          // DMA t+1 done; reads of b done
  }
  #pragma unroll
  for (int r = 0; r < 4; ++r) {
    float x = sums[r];
    x += __shfl_xor(x, 1, 64);
    x += __shfl_xor(x, 2, 64);
    x += __shfl_xor(x, 4, 64);
    x += __shfl_xor(x, 8, 64);
    sums[r] = 1.0f / x;
  }

  // ---------------- pass B: weights + PV ----------------
  f32x4 oacc[4];
  #pragma unroll
  for (int s = 0; s < 4; ++s) oacc[s] = f32x4{0.f, 0.f, 0.f, 0.f};

  stage_K(0, 0);
  stage_V(0, 0);
  __syncthreads();

  for (int t = 0; t < NT; ++t) {
    const int b = t & 1;
    if (t + 1 < NT) { stage_K(t + 1, b ^ 1); stage_V(t + 1, b ^ 1); }
    unsigned long long mb[4];
    #pragma unroll
    for (int r = 0; r < 4; ++r) mb[r] = brow[r * 32 + t];
    f32x4 acc[4];
    #pragma unroll
    for (int s = 0; s < 4; ++s) acc[s] = f32x4{0.f, 0.f, 0.f, 0.f};
    qk_tile(b, acc);
    #pragma unroll
    for (int s = 0; s < 4; ++s) {
      #pragma unroll
      for (int r = 0; r < 4; ++r) {
        const int m   = (int)((mb[r] >> (s * 16 + bsh)) & 1ull);
        const float e = m ? 0.f : __builtin_amdgcn_exp2f(acc[s][r]);
        const float wn = e * sums[r];
        out_w[mofs + (size_t)r * S_LEN + t * 64 + s * 16] = wn;
        p_lds[w][(lq << 2) + r][s * 16 + l15] = f2bf(wn);
      }
    }
    __builtin_amdgcn_wave_barrier();
    #pragma unroll
    for (int c = 0; c < 2; ++c) {
      const bf16x8 pa = *(const bf16x8*)&p_lds[w][l15][c * 32 + (lq << 3)];
      #pragma unroll
      for (int s = 0; s < 4; ++s) {
        const int off = (s * 16 + l15) * 64 + (((((c << 2) | lq)) ^ (l15 & 7)) << 3);
        const bf16x8 vb = *(const bf16x8*)(&vt_s[b][0][0] + off);
        oacc[s] = __builtin_amdgcn_mfma_f32_16x16x32_bf16(pa, vb, oacc[s], 0, 0, 0);
      }
    }
    __builtin_amdgcn_wave_barrier();
    __syncthreads();                          // DMA t+1 done; reads of b done
  }

  #pragma unroll
  for (int s = 0; s < 4; ++s) {
    #pragma unroll
    for (int r = 0; r < 4; ++r) {
      out_o[oofs + (size_t)r * DK + s * 16] = oacc[s][r];
    }
  }
}

// ---------------------------------------------------------------------------
extern "C" void kernel_launch(void* const* d_in, const int* in_sizes, int n_in,
                              void* d_out, int out_size, void* d_ws, size_t ws_size,
                              hipStream_t stream) {
  (void)in_sizes; (void)n_in; (void)out_size; (void)ws_size;
  const float* q = (const float*)d_in[0];
  const float* k = (const float*)d_in[1];
  const float* v = (const float*)d_in[2];
  const int* mask = (const int*)d_in[3];      // bool_ -> int32

  float* out_o = (float*)d_out;               // [B,H,S,D] fp32
  float* out_w = out_o + (size_t)O_ELEMS;     // [B,H,S,S] fp32

  // workspace: K_hi, K_lo, V_t (3 x 16.8 MB) + packed mask bits (33.6 MB)
  unsigned short* k_hi = (unsigned short*)d_ws;
  unsigned short* k_lo = k_hi + (size_t)O_ELEMS;
  unsigned short* v_t  = k_lo + (size_t)O_ELEMS;
  unsigned int*   bits = (unsigned int*)(v_t + (size_t)O_ELEMS);

  cvt_k_kernel<<<O_ELEMS / (256 * 4), 256, 0, stream>>>(k, k_hi, k_lo);
  transpose_v_kernel<<<2048, 256, 0, stream>>>(v, v_t);
  pack_mask_kernel<<<(int)(MASK_ELEMS / (256 * 32)), 256, 0, stream>>>(mask, bits);
  attn_main<<<2048, 256, 0, stream>>>(q, (const unsigned long long*)bits,
                                      k_hi, k_lo, v_t, out_o, out_w);
}

// Round 5
// 834.955 us; speedup vs baseline: 1.9029x; 1.1531x over previous
//
#include <hip/hip_runtime.h>
#include <hip/hip_bf16.h>

// Problem constants (B=4, H=16, S=2048, D=64, fp32).
#define S_LEN 2048
#define DK    64
#define KT    64                   // number of 32-wide k-tiles
#define O_ELEMS (4 * 16 * 2048 * 64)       // 8388608 = B*H*S*D
#define MASK_ELEMS (4ull * 16 * 2048 * 2048) // 268435456

typedef float f32x4  __attribute__((ext_vector_type(4)));
typedef short bf16x8 __attribute__((ext_vector_type(8)));

static __device__ __forceinline__ unsigned short f2bf(float f) {
  unsigned int u = __builtin_bit_cast(unsigned int, f);
  u += 0x7fffu + ((u >> 16) & 1u);
  return (unsigned short)(u >> 16);
}
static __device__ __forceinline__ float bf2f(unsigned short h) {
  unsigned int u = ((unsigned int)h) << 16;
  return __builtin_bit_cast(float, u);
}

// async global->LDS, 16B per lane; LDS dest = wave-uniform base + lane*16
static __device__ __forceinline__ void gload_lds16(const void* g, void* l) {
  __builtin_amdgcn_global_load_lds(
      (const __attribute__((address_space(1))) unsigned int*)g,
      (__attribute__((address_space(3))) unsigned int*)l, 16, 0, 0);
}

// ---------------------------------------------------------------------------
// K -> (K_hi, K_lo) bf16 split. Same [B,H,S,D] layout. grid 8192 x 256.
__global__ __launch_bounds__(256) void cvt_k_kernel(
    const float* __restrict__ k,
    unsigned short* __restrict__ k_hi,
    unsigned short* __restrict__ k_lo) {
  int i = blockIdx.x * 256 + threadIdx.x;
  float4 v = ((const float4*)k)[i];
  ushort4 h, l;
  h.x = f2bf(v.x); l.x = f2bf(v.x - bf2f(h.x));
  h.y = f2bf(v.y); l.y = f2bf(v.y - bf2f(h.y));
  h.z = f2bf(v.z); l.z = f2bf(v.z - bf2f(h.z));
  h.w = f2bf(v.w); l.w = f2bf(v.w - bf2f(h.w));
  ((ushort4*)k_hi)[i] = h;
  ((ushort4*)k_lo)[i] = l;
}

// ---------------------------------------------------------------------------
// V [bh][j][d] fp32 -> V_t [bh][d][j] bf16. grid 2048.
__global__ __launch_bounds__(256) void transpose_v_kernel(
    const float* __restrict__ v,
    unsigned short* __restrict__ v_t) {
  __shared__ float tile[64][65];
  const int b  = blockIdx.x;
  const int bh = b >> 5;
  const int j0 = (b & 31) << 6;
  const int t  = threadIdx.x;
  #pragma unroll
  for (int i = 0; i < 4; ++i) {
    int flat = i * 256 + t;
    int jl   = flat >> 4;
    int f4   = flat & 15;
    float4 x = *(const float4*)(v + ((size_t)bh * S_LEN + j0 + jl) * DK + f4 * 4);
    tile[jl][f4 * 4 + 0] = x.x;
    tile[jl][f4 * 4 + 1] = x.y;
    tile[jl][f4 * 4 + 2] = x.z;
    tile[jl][f4 * 4 + 3] = x.w;
  }
  __syncthreads();
  #pragma unroll
  for (int i = 0; i < 4; ++i) {
    int flat = i * 256 + t;
    int d    = flat >> 4;
    int jg   = (flat & 15) << 2;
    ushort4 o;
    o.x = f2bf(tile[jg + 0][d]);
    o.y = f2bf(tile[jg + 1][d]);
    o.z = f2bf(tile[jg + 2][d]);
    o.w = f2bf(tile[jg + 3][d]);
    *(ushort4*)(v_t + ((size_t)bh * DK + d) * S_LEN + j0 + jg) = o;
  }
}

// ---------------------------------------------------------------------------
// mask int32 -> bit-packed 32:1, linear bit order.
__global__ __launch_bounds__(256) void pack_mask_kernel(
    const int* __restrict__ mask,
    unsigned int* __restrict__ bits) {
  const size_t tidg = (size_t)blockIdx.x * 256 + threadIdx.x;
  const int4* mp = (const int4*)(mask + tidg * 32);
  unsigned int b = 0;
  #pragma unroll
  for (int i = 0; i < 8; ++i) {
    int4 m = mp[i];
    b |= (unsigned)(m.x != 0) << (i * 4 + 0);
    b |= (unsigned)(m.y != 0) << (i * 4 + 1);
    b |= (unsigned)(m.z != 0) << (i * 4 + 2);
    b |= (unsigned)(m.w != 0) << (i * 4 + 3);
  }
  bits[tidg] = b;
}

// ---------------------------------------------------------------------------
// Fused attention. Block = 64 q-rows of one (b,h); 4 waves x 16 rows.
// KVBLK=32 tiles, triple-buffered LDS, 2-ahead prefetch, counted vmcnt,
// raw s_barrier (ONE per iteration) -- DMA stays in flight across barriers.
// LDS exactly 40KB -> 4 blocks/CU (16 waves/CU).
__global__ __launch_bounds__(256, 4) void attn_main(
    const float* __restrict__ q,
    const unsigned int* __restrict__ bits,
    const unsigned short* __restrict__ k_hi,
    const unsigned short* __restrict__ k_lo,
    const unsigned short* __restrict__ v_t,
    float* __restrict__ out_o,
    float* __restrict__ out_w) {
  const int blk = blockIdx.x;                 // 0..2047
  const int id  = ((blk & 7) << 8) | (blk >> 3);  // XCD-contig bh ranges
  const int bh  = id >> 5;                    // 0..63
  const int q0  = (id & 31) << 6;             // q-tile * 64

  const int tid = threadIdx.x;
  const int w   = tid >> 6;                   // wave 0..3
  const int ln  = tid & 63;
  const int l15 = ln & 15;
  const int lq  = ln >> 4;                    // 0..3

  __shared__ __align__(16) unsigned short kh_s[3][32][64];  // 12 KB
  __shared__ __align__(16) unsigned short kl_s[3][32][64];  // 12 KB
  __shared__ __align__(16) unsigned short vt_s[3][64][32];  // 12 KB
  __shared__ __align__(16) unsigned short p_lds[4][16][32]; //  4 KB (swizzled)

  // ---- staging source addressing (swizzle at the source, rule #21) ----
  // K tile rows: wave w stages rows [8w,8w+8); lane -> row 8w+(ln>>3), chunk ln&7
  const int r8 = ln >> 3, c8 = ln & 7;
  const size_t kst = ((size_t)bh * S_LEN + 8 * w + r8) * DK + ((size_t)(c8 ^ r8) << 3);
  // V^T tile rows (d): wave w stages rows [16w,16w+16); lane -> row 16w+(ln>>2),
  // chunk (ln&3) ^ ((row>>1)&3) = (ln&3) ^ ((ln>>3)&3)
  const int r4 = ln >> 2;
  const size_t vst = ((size_t)bh * DK + 16 * w + r4) * S_LEN +
                     ((size_t)((ln & 3) ^ ((ln >> 3) & 3)) << 3);

  auto stage_K = [&](int t, int b) {
    gload_lds16(k_hi + kst + (size_t)t * (32 * DK), &kh_s[b][8 * w][0]);
    gload_lds16(k_lo + kst + (size_t)t * (32 * DK), &kl_s[b][8 * w][0]);
  };
  auto stage_V = [&](int t, int b) {
    gload_lds16(v_t + vst + (size_t)t * 32, &vt_s[b][16 * w][0]);
  };

  // Q loads issued BEFORE staging so their waits don't drain the DMA
  const float* qp = q + ((size_t)bh * S_LEN + q0 + (w << 4) + l15) * DK + (lq << 3);
  const float4 qa0 = *(const float4*)(qp);
  const float4 qb0 = *(const float4*)(qp + 4);
  const float4 qa1 = *(const float4*)(qp + 32);
  const float4 qb1 = *(const float4*)(qp + 36);

  stage_K(0, 0);
  stage_K(1, 1);

  // ---- Q A-fragments: scale by log2(e)/8, split hi/lo ----
  bf16x8 qh[2], ql[2];
  {
    const float sc = 0.125f * 1.4426950408889634f;
    float vv0[8] = {qa0.x, qa0.y, qa0.z, qa0.w, qb0.x, qb0.y, qb0.z, qb0.w};
    float vv1[8] = {qa1.x, qa1.y, qa1.z, qa1.w, qb1.x, qb1.y, qb1.z, qb1.w};
    #pragma unroll
    for (int i = 0; i < 8; ++i) {
      float s0 = vv0[i] * sc;
      unsigned short h0 = f2bf(s0);
      qh[0][i] = (short)h0; ql[0][i] = (short)f2bf(s0 - bf2f(h0));
      float s1 = vv1[i] * sc;
      unsigned short h1 = f2bf(s1);
      qh[1][i] = (short)h1; ql[1][i] = (short)f2bf(s1 - bf2f(h1));
    }
  }

  const size_t rowb = (size_t)bh * S_LEN + q0 + (w << 4) + (lq << 2);
  const size_t mofs = rowb * S_LEN + l15;     // weights offset
  const size_t oofs = rowb * DK + l15;
  const unsigned int* brow = bits + rowb * 64;  // 64 uints per q-row

  // fragment read: row = s*16+l15, chunk ((c<<2)|lq) ^ (l15&7)
  auto qk_tile = [&](int b, f32x4 (&acc)[2]) {
    #pragma unroll
    for (int s = 0; s < 2; ++s) {
      #pragma unroll
      for (int c = 0; c < 2; ++c) {
        const int off = (s * 16 + l15) * 64 + ((((c << 2) | lq) ^ (l15 & 7)) << 3);
        const bf16x8 bhf = *(const bf16x8*)(&kh_s[b][0][0] + off);
        const bf16x8 blf = *(const bf16x8*)(&kl_s[b][0][0] + off);
        acc[s] = __builtin_amdgcn_mfma_f32_16x16x32_bf16(ql[c], bhf, acc[s], 0, 0, 0);
        acc[s] = __builtin_amdgcn_mfma_f32_16x16x32_bf16(qh[c], blf, acc[s], 0, 0, 0);
        acc[s] = __builtin_amdgcn_mfma_f32_16x16x32_bf16(qh[c], bhf, acc[s], 0, 0, 0);
      }
    }
  };

  // ---------------- pass A: row sums of exp2 ----------------
  float sums[4] = {0.f, 0.f, 0.f, 0.f};
  for (int t = 0; t < KT; ++t) {
    const int b = t % 3;
    asm volatile("s_waitcnt vmcnt(2)" ::: "memory");  // tile t landed; t+1 in flight
    __builtin_amdgcn_s_barrier();
    __builtin_amdgcn_sched_barrier(0);
    unsigned mb[4];
    #pragma unroll
    for (int r = 0; r < 4; ++r) mb[r] = brow[r * 64 + t];
    if (t + 2 < KT) stage_K(t + 2, (t + 2) % 3);
    f32x4 acc[2];
    #pragma unroll
    for (int s = 0; s < 2; ++s) acc[s] = f32x4{0.f, 0.f, 0.f, 0.f};
    qk_tile(b, acc);
    #pragma unroll
    for (int s = 0; s < 2; ++s) {
      #pragma unroll
      for (int r = 0; r < 4; ++r) {
        const int m = (int)((mb[r] >> (s * 16 + l15)) & 1u);
        sums[r] += m ? 0.f : __builtin_amdgcn_exp2f(acc[s][r]);
      }
    }
  }
  #pragma unroll
  for (int r = 0; r < 4; ++r) {
    float x = sums[r];
    x += __shfl_xor(x, 1, 64);
    x += __shfl_xor(x, 2, 64);
    x += __shfl_xor(x, 4, 64);
    x += __shfl_xor(x, 8, 64);
    sums[r] = 1.0f / x;
  }

  // ---------------- pass B: weights + PV ----------------
  f32x4 oacc[4];
  #pragma unroll
  for (int s = 0; s < 4; ++s) oacc[s] = f32x4{0.f, 0.f, 0.f, 0.f};

  __builtin_amdgcn_s_barrier();               // all pass-A LDS reads done
  __builtin_amdgcn_sched_barrier(0);
  stage_K(0, 0); stage_V(0, 0);
  stage_K(1, 1); stage_V(1, 1);

  for (int t = 0; t < KT; ++t) {
    const int b = t % 3;
    asm volatile("s_waitcnt vmcnt(3)" ::: "memory");  // tile t landed; t+1 in flight
    __builtin_amdgcn_s_barrier();
    __builtin_amdgcn_sched_barrier(0);
    unsigned mb[4];
    #pragma unroll
    for (int r = 0; r < 4; ++r) mb[r] = brow[r * 64 + t];
    if (t + 2 < KT) { stage_K(t + 2, (t + 2) % 3); stage_V(t + 2, (t + 2) % 3); }
    f32x4 acc[2];
    #pragma unroll
    for (int s = 0; s < 2; ++s) acc[s] = f32x4{0.f, 0.f, 0.f, 0.f};
    qk_tile(b, acc);
    #pragma unroll
    for (int s = 0; s < 2; ++s) {
      #pragma unroll
      for (int r = 0; r < 4; ++r) {
        const int m   = (int)((mb[r] >> (s * 16 + l15)) & 1u);
        const float e = m ? 0.f : __builtin_amdgcn_exp2f(acc[s][r]);
        const float wn = e * sums[r];
        out_w[mofs + (size_t)r * S_LEN + t * 32 + s * 16] = wn;
        // swizzled p_lds write: logical col = s*16+l15
        const int row   = (lq << 2) + r;
        const int chunk = ((s << 1) | (l15 >> 3)) ^ ((row >> 1) & 3);
        p_lds[w][row][(chunk << 3) | (l15 & 7)] = f2bf(wn);
      }
    }
    __builtin_amdgcn_wave_barrier();
    const bf16x8 pa = *(const bf16x8*)&p_lds[w][l15][(lq ^ ((l15 >> 1) & 3)) << 3];
    #pragma unroll
    for (int s = 0; s < 4; ++s) {
      const bf16x8 vb =
          *(const bf16x8*)&vt_s[b][s * 16 + l15][(lq ^ ((l15 >> 1) & 3)) << 3];
      oacc[s] = __builtin_amdgcn_mfma_f32_16x16x32_bf16(pa, vb, oacc[s], 0, 0, 0);
    }
    __builtin_amdgcn_wave_barrier();
  }

  #pragma unroll
  for (int s = 0; s < 4; ++s) {
    #pragma unroll
    for (int r = 0; r < 4; ++r) {
      out_o[oofs + (size_t)r * DK + s * 16] = oacc[s][r];
    }
  }
}

// ---------------------------------------------------------------------------
extern "C" void kernel_launch(void* const* d_in, const int* in_sizes, int n_in,
                              void* d_out, int out_size, void* d_ws, size_t ws_size,
                              hipStream_t stream) {
  (void)in_sizes; (void)n_in; (void)out_size; (void)ws_size;
  const float* q = (const float*)d_in[0];
  const float* k = (const float*)d_in[1];
  const float* v = (const float*)d_in[2];
  const int* mask = (const int*)d_in[3];      // bool_ -> int32

  float* out_o = (float*)d_out;               // [B,H,S,D] fp32
  float* out_w = out_o + (size_t)O_ELEMS;     // [B,H,S,S] fp32

  // workspace: K_hi, K_lo, V_t (3 x 16.8 MB) + packed mask bits (33.6 MB)
  unsigned short* k_hi = (unsigned short*)d_ws;
  unsigned short* k_lo = k_hi + (size_t)O_ELEMS;
  unsigned short* v_t  = k_lo + (size_t)O_ELEMS;
  unsigned int*   bits = (unsigned int*)(v_t + (size_t)O_ELEMS);

  cvt_k_kernel<<<O_ELEMS / (256 * 4), 256, 0, stream>>>(k, k_hi, k_lo);
  transpose_v_kernel<<<2048, 256, 0, stream>>>(v, v_t);
  pack_mask_kernel<<<(int)(MASK_ELEMS / (256 * 32)), 256, 0, stream>>>(mask, bits);
  attn_main<<<2048, 256, 0, stream>>>(q, bits, k_hi, k_lo, v_t, out_o, out_w);
}